// Round 1
// baseline (372.673 us; speedup 1.0000x reference)
//
#include <hip/hip_runtime.h>
#include <math.h>

#define HW2 262144              // 512*512
#define TWO_PI     6.28318530717958647693f
#define INV_TWO_PI 0.15915494309189533577f
#define LOG2E      1.44269504088896340736f

// Per-(layer,channel) folded gabor constants, 8 floats each:
// [A, B, C, mu0, mu1, w0/2pi, w1/2pi, b/2pi]
// g = exp2(A*d0^2 + B*d0*d1 + C*d1^2),  d = x - mu
// sin term = v_sin(w0r*x0 + w1r*x1 + br)   (v_sin takes revolutions)
__global__ void gabor_precompute(const float* __restrict__ filt_w,
                                 const float* __restrict__ filt_b,
                                 const float* __restrict__ mu,
                                 const float* __restrict__ gamma,
                                 const float* __restrict__ theta,
                                 float* __restrict__ pc) {
    int i = blockIdx.x * blockDim.x + threadIdx.x;   // 0 .. 319  (= l*64 + c)
    if (i >= 5 * 64) return;
    float ang = TWO_PI * theta[i];
    float cs = cosf(ang), sn = sinf(ang);
    float g0 = gamma[i * 2 + 0], g1 = gamma[i * 2 + 1];
    float g0s = g0 * g0, g1s = g1 * g1;
    float cs2 = cs * cs, sn2 = sn * sn;
    float A = -0.5f * LOG2E * (g0s * cs2 + g1s * sn2);
    float Bq = -LOG2E * (cs * sn * (g0s - g1s));
    float Cq = -0.5f * LOG2E * (g0s * sn2 + g1s * cs2);
    float* o = pc + i * 8;
    o[0] = A;  o[1] = Bq; o[2] = Cq;
    o[3] = mu[i * 2 + 0];
    o[4] = mu[i * 2 + 1];
    o[5] = filt_w[i * 2 + 0] * INV_TWO_PI;
    o[6] = filt_w[i * 2 + 1] * INV_TWO_PI;
    o[7] = filt_b[i] * INV_TWO_PI;
}

__device__ __forceinline__ float gabor_eval(const float* __restrict__ q,
                                            float x0, float x1) {
    float d0 = x0 - q[3];
    float d1 = x1 - q[4];
    float t  = fmaf(q[0] * d0, d0, fmaf(q[1] * d0, d1, q[2] * d1 * d1));
    float e  = __builtin_amdgcn_exp2f(t);
    float sarg = fmaf(q[5], x0, fmaf(q[6], x1, q[7]));
    return e * __builtin_amdgcn_sinf(sarg);
}

__global__ __launch_bounds__(256) void gabor_main(
    const float* __restrict__ x, const float* __restrict__ lin_w,
    const float* __restrict__ lin_b, const float* __restrict__ out_w,
    const float* __restrict__ out_b, const float* __restrict__ pc,
    float* __restrict__ out) {
    int p   = blockIdx.x * 256 + threadIdx.x;   // 0 .. 524287
    int b   = p >> 18;                          // pixel batch
    int pix = p & (HW2 - 1);
    const float* xb = x + b * (2 * HW2) + pix;
    float x0 = xb[0];
    float x1 = xb[HW2];

    float hid[64];
#pragma unroll
    for (int c = 0; c < 64; ++c)
        hid[c] = gabor_eval(pc + c * 8, x0, x1);

#pragma unroll 1
    for (int l = 1; l <= 4; ++l) {
        const float* W  = lin_w + (l - 1) * 4096;
        const float* Bv = lin_b + (l - 1) * 64;
        const float* Q  = pc + l * 512;
        float nh[64];
#pragma unroll
        for (int c = 0; c < 64; ++c) {
            float acc = Bv[c];
            const float* wr = W + c * 64;
#pragma unroll
            for (int k = 0; k < 64; ++k)
                acc = fmaf(wr[k], hid[k], acc);
            nh[c] = gabor_eval(Q + c * 8, x0, x1) * acc;
        }
#pragma unroll
        for (int c = 0; c < 64; ++c) hid[c] = nh[c];
    }

    float* ob = out + b * (3 * HW2) + pix;
#pragma unroll
    for (int o = 0; o < 3; ++o) {
        float acc = out_b[o];
        const float* wr = out_w + o * 64;
#pragma unroll
        for (int k = 0; k < 64; ++k)
            acc = fmaf(wr[k], hid[k], acc);
        ob[o * HW2] = acc;
    }
}

extern "C" void kernel_launch(void* const* d_in, const int* in_sizes, int n_in,
                              void* d_out, int out_size, void* d_ws, size_t ws_size,
                              hipStream_t stream) {
    const float* x      = (const float*)d_in[0];
    const float* filt_w = (const float*)d_in[1];
    const float* filt_b = (const float*)d_in[2];
    const float* mu     = (const float*)d_in[3];
    const float* gamma  = (const float*)d_in[4];
    const float* theta  = (const float*)d_in[5];
    const float* lin_w  = (const float*)d_in[6];
    const float* lin_b  = (const float*)d_in[7];
    const float* out_w  = (const float*)d_in[8];
    const float* out_b  = (const float*)d_in[9];
    float* pc = (float*)d_ws;   // 5*64*8 floats = 10 KB

    gabor_precompute<<<1, 320, 0, stream>>>(filt_w, filt_b, mu, gamma, theta, pc);
    gabor_main<<<2048, 256, 0, stream>>>(x, lin_w, lin_b, out_w, out_b, pc,
                                         (float*)d_out);
}

// Round 2
// 290.546 us; speedup vs baseline: 1.2827x; 1.2827x over previous
//
#include <hip/hip_runtime.h>
#include <math.h>

#define HW2 262144              // 512*512
#define TWO_PI     6.28318530717958647693f
#define INV_TWO_PI 0.15915494309189533577f
#define LOG2E      1.44269504088896340736f

// Per-(layer,channel) folded gabor constants, 8 floats each:
// [A, B, C, mu0, mu1, w0/2pi, w1/2pi, b/2pi]
// g = exp2(A*d0^2 + B*d0*d1 + C*d1^2),  d = x - mu
// sin term = v_sin(w0r*x0 + w1r*x1 + br)   (v_sin takes revolutions)
__global__ void gabor_precompute(const float* __restrict__ filt_w,
                                 const float* __restrict__ filt_b,
                                 const float* __restrict__ mu,
                                 const float* __restrict__ gamma,
                                 const float* __restrict__ theta,
                                 float* __restrict__ pc) {
    int i = blockIdx.x * blockDim.x + threadIdx.x;   // 0 .. 319  (= l*64 + c)
    if (i >= 5 * 64) return;
    float ang = TWO_PI * theta[i];
    float cs = cosf(ang), sn = sinf(ang);
    float g0 = gamma[i * 2 + 0], g1 = gamma[i * 2 + 1];
    float g0s = g0 * g0, g1s = g1 * g1;
    float cs2 = cs * cs, sn2 = sn * sn;
    float A = -0.5f * LOG2E * (g0s * cs2 + g1s * sn2);
    float Bq = -LOG2E * (cs * sn * (g0s - g1s));
    float Cq = -0.5f * LOG2E * (g0s * sn2 + g1s * cs2);
    float* o = pc + i * 8;
    o[0] = A;  o[1] = Bq; o[2] = Cq;
    o[3] = mu[i * 2 + 0];
    o[4] = mu[i * 2 + 1];
    o[5] = filt_w[i * 2 + 0] * INV_TWO_PI;
    o[6] = filt_w[i * 2 + 1] * INV_TWO_PI;
    o[7] = filt_b[i] * INV_TWO_PI;
}

__device__ __forceinline__ float gabor_eval(const float* __restrict__ q,
                                            float x0, float x1) {
    float d0 = x0 - q[3];
    float d1 = x1 - q[4];
    float t  = fmaf(q[0] * d0, d0, fmaf(q[1] * d0, d1, q[2] * d1 * d1));
    float e  = __builtin_amdgcn_exp2f(t);
    float sarg = fmaf(q[5], x0, fmaf(q[6], x1, q[7]));
    return e * __builtin_amdgcn_sinf(sarg);
}

// __launch_bounds__(256, 2): min 2 waves/EU -> VGPR budget 256. Without the
// second arg the compiler capped at 72 VGPR and spilled hid[64]/nh[64] to
// scratch (R1: VALUBusy 40%, dur 373us). ~190 VGPR needed for full residency.
__global__ __launch_bounds__(256, 2) void gabor_main(
    const float* __restrict__ x, const float* __restrict__ lin_w,
    const float* __restrict__ lin_b, const float* __restrict__ out_w,
    const float* __restrict__ out_b, const float* __restrict__ pc,
    float* __restrict__ out) {
    int p   = blockIdx.x * 256 + threadIdx.x;   // 0 .. 524287
    int b   = p >> 18;                          // pixel batch
    int pix = p & (HW2 - 1);
    const float* xb = x + b * (2 * HW2) + pix;
    float x0 = xb[0];
    float x1 = xb[HW2];

    float hid[64];
#pragma unroll
    for (int c = 0; c < 64; ++c)
        hid[c] = gabor_eval(pc + c * 8, x0, x1);

#pragma unroll 1
    for (int l = 1; l <= 4; ++l) {
        const float* W  = lin_w + (l - 1) * 4096;
        const float* Bv = lin_b + (l - 1) * 64;
        const float* Q  = pc + l * 512;
        float nh[64];
#pragma unroll
        for (int c = 0; c < 64; ++c) {
            const float* wr = W + c * 64;
            // two accumulator chains -> dep-latency hiding within the wave
            float a0 = Bv[c];
            float a1 = 0.0f;
#pragma unroll
            for (int k = 0; k < 64; k += 2) {
                a0 = fmaf(wr[k],     hid[k],     a0);
                a1 = fmaf(wr[k + 1], hid[k + 1], a1);
            }
            nh[c] = gabor_eval(Q + c * 8, x0, x1) * (a0 + a1);
        }
#pragma unroll
        for (int c = 0; c < 64; ++c) hid[c] = nh[c];
    }

    float* ob = out + b * (3 * HW2) + pix;
#pragma unroll
    for (int o = 0; o < 3; ++o) {
        const float* wr = out_w + o * 64;
        float a0 = out_b[o];
        float a1 = 0.0f;
#pragma unroll
        for (int k = 0; k < 64; k += 2) {
            a0 = fmaf(wr[k],     hid[k],     a0);
            a1 = fmaf(wr[k + 1], hid[k + 1], a1);
        }
        ob[o * HW2] = a0 + a1;
    }
}

extern "C" void kernel_launch(void* const* d_in, const int* in_sizes, int n_in,
                              void* d_out, int out_size, void* d_ws, size_t ws_size,
                              hipStream_t stream) {
    const float* x      = (const float*)d_in[0];
    const float* filt_w = (const float*)d_in[1];
    const float* filt_b = (const float*)d_in[2];
    const float* mu     = (const float*)d_in[3];
    const float* gamma  = (const float*)d_in[4];
    const float* theta  = (const float*)d_in[5];
    const float* lin_w  = (const float*)d_in[6];
    const float* lin_b  = (const float*)d_in[7];
    const float* out_w  = (const float*)d_in[8];
    const float* out_b  = (const float*)d_in[9];
    float* pc = (float*)d_ws;   // 5*64*8 floats = 10 KB

    gabor_precompute<<<1, 320, 0, stream>>>(filt_w, filt_b, mu, gamma, theta, pc);
    gabor_main<<<2048, 256, 0, stream>>>(x, lin_w, lin_b, out_w, out_b, pc,
                                         (float*)d_out);
}